// Round 9
// baseline (579.236 us; speedup 1.0000x reference)
//
#include <hip/hip_runtime.h>
#include <math.h>

#define P 128

typedef __attribute__((ext_vector_type(8))) short short8;
typedef __attribute__((ext_vector_type(4))) float f32x4;

static __device__ __forceinline__ float lrelu(float x){ return x > 0.f ? x : 0.01f*x; }
static __device__ __forceinline__ float bflo(unsigned u){ union{unsigned u; float f;} c; c.u = u << 16; return c.f; }
static __device__ __forceinline__ float bfhi(unsigned u){ union{unsigned u; float f;} c; c.u = u & 0xffff0000u; return c.f; }
static __device__ __forceinline__ unsigned fbits(float f){ union{float f; unsigned u;} c; c.f = f; return c.u; }
// round-to-nearest-even f32->bf16, packed pair (lo = first)
static __device__ __forceinline__ unsigned packbf(float x, float y){
  unsigned ux = fbits(x); ux += 0x7fffu + ((ux >> 16) & 1u);
  unsigned uy = fbits(y); uy += 0x7fffu + ((uy >> 16) & 1u);
  return (ux >> 16) | (uy & 0xffff0000u);
}

// ---------------- CSR build (by dst) ----------------
__global__ void k_hist(const int* __restrict__ dst, int E, int* __restrict__ cnt){
  int i = blockIdx.x*blockDim.x + threadIdx.x;
  int i4 = i*4;
  if(i4 + 4 <= E){
    int4 d = *(const int4*)(dst + i4);
    atomicAdd(&cnt[d.x], 1); atomicAdd(&cnt[d.y], 1);
    atomicAdd(&cnt[d.z], 1); atomicAdd(&cnt[d.w], 1);
  } else {
    for(int j = i4; j < E; ++j) atomicAdd(&cnt[dst[j]], 1);
  }
}

__global__ void k_scan1(const int* __restrict__ cnt, int N, int* __restrict__ off, int* __restrict__ partial){
  __shared__ int s[256];
  int t = threadIdx.x, i = blockIdx.x*256 + t;
  int v = (i < N) ? cnt[i] : 0;
  s[t] = v; __syncthreads();
  for(int o = 1; o < 256; o <<= 1){
    int x = (t >= o) ? s[t-o] : 0; __syncthreads();
    s[t] += x; __syncthreads();
  }
  if(i < N) off[i] = s[t];
  if(t == 255) partial[blockIdx.x] = s[255];
}

__global__ void k_scan2(int* __restrict__ partial, int nb){
  __shared__ int s[512];
  int t = threadIdx.x;
  int v = (t < nb) ? partial[t] : 0;
  s[t] = v; __syncthreads();
  for(int o = 1; o < 512; o <<= 1){
    int x = (t >= o) ? s[t-o] : 0; __syncthreads();
    s[t] += x; __syncthreads();
  }
  if(t < nb) partial[t] = s[t] - v;
}

__global__ void k_scan3(const int* __restrict__ cnt, int N, int E, int* __restrict__ off, const int* __restrict__ partial){
  int i = blockIdx.x*256 + threadIdx.x;
  if(i < N) off[i] = off[i] - cnt[i] + partial[blockIdx.x];
  if(i == 0) off[N] = E;
}

__global__ void k_scatter(const int* __restrict__ ei, const float* __restrict__ ea, int E,
                          const int* __restrict__ off, int* __restrict__ cur,
                          int* __restrict__ csr_src, float* __restrict__ csr_attr){
  const int* src = ei; const int* dst = ei + E;
  int i = blockIdx.x*blockDim.x + threadIdx.x;
  int i4 = i*4;
  if(i4 + 4 <= E){
    int4   s = *(const int4*)(src + i4);
    int4   d = *(const int4*)(dst + i4);
    float4 a = *(const float4*)(ea + i4);
    int p0 = off[d.x] + atomicAdd(&cur[d.x], 1);
    int p1 = off[d.y] + atomicAdd(&cur[d.y], 1);
    int p2 = off[d.z] + atomicAdd(&cur[d.z], 1);
    int p3 = off[d.w] + atomicAdd(&cur[d.w], 1);
    csr_src[p0] = s.x; csr_attr[p0] = a.x;
    csr_src[p1] = s.y; csr_attr[p1] = a.y;
    csr_src[p2] = s.z; csr_attr[p2] = a.z;
    csr_src[p3] = s.w; csr_attr[p3] = a.w;
  } else {
    for(int j = i4; j < E; ++j){
      int d = dst[j];
      int p = off[d] + atomicAdd(&cur[d], 1);
      csr_src[p] = src[j]; csr_attr[p] = ea[j];
    }
  }
}

// ---------------- converters ----------------
__global__ void k_cvt(const float2* __restrict__ in, unsigned* __restrict__ out, int n){
  int i = blockIdx.x*256 + threadIdx.x;
  if(i < n){ float2 v = in[i]; out[i] = packbf(v.x, v.y); }
}

// blocks 0..127 -> W1T, 128..255 -> W2T, 256 -> W2Tx (extended-K B rows)
__global__ void k_wprep(const float* __restrict__ W1, const float* __restrict__ W2,
                        unsigned* __restrict__ W1T, unsigned* __restrict__ W2T,
                        const float* __restrict__ Wv, const float* __restrict__ bv,
                        const float* __restrict__ Wp, const float* __restrict__ bp,
                        const float* __restrict__ Wd, const float* __restrict__ bd,
                        const float* __restrict__ b1, const float* __restrict__ b2,
                        unsigned* __restrict__ W2Tx){
  int b = blockIdx.x, t = threadIdx.x;
  if(b < 256){
    if(t < 64){
      const float* W = (b < 128) ? W1 : W2;
      unsigned* WT   = (b < 128) ? W1T : W2T;
      int j = b & 127, k2 = t;
      float a = W[(size_t)(2*k2)*P + j], c = W[(size_t)(2*k2+1)*P + j];
      WT[(size_t)j*64 + k2] = packbf(a, c);
    }
  } else {
    // extra B: [j][16 u32] covering k-slots 128..159
    int j = t;  // 128 threads
    unsigned q[16];
    #pragma unroll
    for(int i = 0; i < 16; ++i) q[i] = 0;
    q[0] = packbf(Wv[j],     Wv[128+j]);
    q[1] = packbf(Wp[j],     Wp[128+j]);
    q[2] = packbf(Wp[256+j], Wd[j]);
    q[3] = packbf(Wd[128+j], b1[j] + b2[j]);
    q[4] = packbf(bv[j],     bp[j]);
    q[5] = packbf(bd[j],     0.f);
    uint4* dst = (uint4*)(W2Tx + (size_t)j*16);
    #pragma unroll
    for(int i = 0; i < 4; ++i) dst[i] = make_uint4(q[4*i], q[4*i+1], q[4*i+2], q[4*i+3]);
  }
}

// ============ base builder: baseB = [aggt | xfeat] @ [W2 | Wtype]^T  (extended K=160) ============
// block: 512 threads = 8 waves; 64 rows x 128 cols.
__global__ __launch_bounds__(512) void k_gemmB(
    const int* __restrict__ off, const float* __restrict__ csr_attr,
    const float* __restrict__ W3, const float* __restrict__ b3,
    const short8* __restrict__ WT, const short8* __restrict__ WTx,
    const float* __restrict__ xv, const float* __restrict__ xp, const float* __restrict__ xd,
    int NV, int NP_, int N, unsigned* __restrict__ Out){
  __shared__ __align__(16) unsigned shu[5376];  // A-main u32[0,4096) swizzled; A-extra u32[4096,5376) pitch 20
  __shared__ int sbound[8][9];
  int t = threadIdx.x, w = t >> 6, l = t & 63;
  int bm = blockIdx.x * 64;

  if(l < 9) sbound[w][l] = off[min(bm + w*8 + l, N)];

  // gather phase: flat edge-range walk, batches of 16 contiguous attr loads, double-buffered
  {
    float w0 = W3[2*l], w1 = W3[2*l+1];
    float c0 = b3[2*l], c1 = b3[2*l+1];
    int e0 = sbound[w][0], eEnd = sbound[w][8];
    int cur = 0, nb = sbound[w][1];
    float ax = 0.f, ay = 0.f;
    auto flushTo = [&](int edge){
      while(edge >= nb){
        int row = w*8 + cur;
        shu[(row*256 + ((l*4) ^ ((row&7)<<4))) >> 2] = packbf(ax, ay);
        ax = 0.f; ay = 0.f; ++cur; nb = sbound[w][cur + 1];
      }
    };
    auto loadb = [&](float (&buf)[16], int ebase){
      #pragma unroll
      for(int k = 0; k < 16; ++k) buf[k] = csr_attr[ebase + k];
    };
    auto procb = [&](float (&buf)[16], int ebase){
      #pragma unroll
      for(int k = 0; k < 16; ++k){
        flushTo(ebase + k);
        ax += lrelu(fmaf(buf[k], w0, c0));
        ay += lrelu(fmaf(buf[k], w1, c1));
      }
    };
    int nfull = (eEnd - e0) >> 4;
    float va[16], vb[16];
    int b = 0;
    if(nfull > 0) loadb(va, e0);
    for(; b + 2 <= nfull; b += 2){
      loadb(vb, e0 + (b+1)*16);
      procb(va, e0 + b*16);
      if(b + 2 < nfull) loadb(va, e0 + (b+2)*16);
      procb(vb, e0 + (b+1)*16);
    }
    if(b < nfull) procb(va, e0 + b*16);
    int e = e0 + nfull*16;
    if(e < eEnd){
      #pragma unroll
      for(int k = 0; k < 16; ++k) va[k] = csr_attr[min(e + k, eEnd - 1)];
      #pragma unroll
      for(int k = 0; k < 16; ++k){
        if(e + k >= eEnd) break;
        flushTo(e + k);
        ax += lrelu(fmaf(va[k], w0, c0));
        ay += lrelu(fmaf(va[k], w1, c1));
      }
    }
    for(; cur < 8; ++cur){
      int row = w*8 + cur;
      shu[(row*256 + ((l*4) ^ ((row&7)<<4))) >> 2] = packbf(ax, ay);
      ax = 0.f; ay = 0.f;
    }
  }
  // A-extra: row r = t>>3, pair q = t&7 (slots 2q,2q+1); slots 16..31 zero
  {
    int r = t >> 3, q = t & 7;
    int node = bm + r;
    float x0=0.f, x1=0.f, x2=0.f; int ty = 3;
    if(node < N){
      if(node < NV){ ty = 0; x0 = xv[2*node]; x1 = xv[2*node+1]; }
      else if(node < NV + NP_){ int i2 = node - NV; ty = 1; x0 = xp[3*i2]; x1 = xp[3*i2+1]; x2 = xp[3*i2+2]; }
      else { int i2 = node - NV - NP_; ty = 2; x0 = xd[2*i2]; x1 = xd[2*i2+1]; }
    }
    float s0v, s1v;
    switch(q){
      case 0: s0v = (ty==0)?x0:0.f; s1v = (ty==0)?x1:0.f; break;
      case 1: s0v = (ty==1)?x0:0.f; s1v = (ty==1)?x1:0.f; break;
      case 2: s0v = (ty==1)?x2:0.f; s1v = (ty==2)?x0:0.f; break;
      case 3: s0v = (ty==2)?x1:0.f; s1v = (node<N)?1.f:0.f; break;
      case 4: s0v = (ty==0)?1.f:0.f; s1v = (ty==1)?1.f:0.f; break;
      case 5: s0v = (ty==2)?1.f:0.f; s1v = 0.f; break;
      default: s0v = 0.f; s1v = 0.f; break;
    }
    shu[4096 + r*20 + q]     = packbf(s0v, s1v);
    shu[4096 + r*20 + 8 + q] = 0u;
  }
  __syncthreads();

  // MFMA: wave (wm,wn) -> rows wm*16..+16, cols wn*64..+64; K = 160
  int lr = l & 15, lg = l >> 4;
  int wm = w & 3, wn = w >> 2;
  f32x4 acc[4];
  #pragma unroll
  for(int i = 0; i < 4; ++i) acc[i] = (f32x4)0.f;
  int arow = wm*16 + lr;
  #pragma unroll
  for(int ks = 0; ks < 4; ++ks){
    short8 a = *(const short8*)((const char*)shu + arow*256 + ((((ks*4+lg)*16) ^ ((arow&7)<<4))));
    #pragma unroll
    for(int ct = 0; ct < 4; ++ct){
      short8 b = WT[(size_t)(wn*64 + ct*16 + lr)*16 + ks*4 + lg];
      acc[ct] = __builtin_amdgcn_mfma_f32_16x16x32_bf16(a, b, acc[ct], 0, 0, 0);
    }
  }
  {
    short8 a = *(const short8*)&shu[4096 + arow*20 + lg*4];
    #pragma unroll
    for(int ct = 0; ct < 4; ++ct){
      short8 b = WTx[(size_t)(wn*64 + ct*16 + lr)*4 + lg];
      acc[ct] = __builtin_amdgcn_mfma_f32_16x16x32_bf16(a, b, acc[ct], 0, 0, 0);
    }
  }
  __syncthreads();   // A dead; C-chunks may overwrite

  // chunked C transpose + pack (no further epilogue math)
  float* shf = (float*)shu;
  int r = t >> 3, seg = t & 7;
  int row = bm + r;
  #pragma unroll
  for(int h = 0; h < 2; ++h){
    if(wn == h){
      #pragma unroll
      for(int ct = 0; ct < 4; ++ct)
        #pragma unroll
        for(int rr = 0; rr < 4; ++rr)
          shf[(wm*16 + lg*4 + rr)*68 + ct*16 + lr] = acc[ct][rr];
    }
    __syncthreads();
    if(row < N){
      float4 v0 = *(const float4*)&shf[r*68 + seg*8];
      float4 v1 = *(const float4*)&shf[r*68 + seg*8 + 4];
      *(uint4*)&Out[(size_t)row*64 + h*32 + seg*4] =
        make_uint4(packbf(v0.x,v0.y), packbf(v0.z,v0.w), packbf(v1.x,v1.y), packbf(v1.z,v1.w));
    }
    __syncthreads();
  }
}

// ============ fused iteration: Out = lrelu( (segment_sum mu[src]) @ W1^T + baseB ) ============
// block: 512 threads = 8 waves; 64 rows x 128 cols.
// Gather: flat edge-range walk, 16-load batches, double-buffered (loads of batch k+1
// issued before processing batch k -> latency hidden under accumulate VALU).
__global__ __launch_bounds__(512) void k_fused(
    const int* __restrict__ off, const int* __restrict__ csr_src,
    const unsigned* __restrict__ mu, const short8* __restrict__ WT,
    const unsigned* __restrict__ baseB, unsigned* __restrict__ Out, int N){
  __shared__ __align__(16) float shf[64*68];   // 17408B; front 16KB doubles as swizzled A-tile
  __shared__ int sbound[8][9];
  int t = threadIdx.x, w = t >> 6, l = t & 63;
  int bm = blockIdx.x * 64;
  unsigned* Albs = (unsigned*)shf;

  if(l < 9) sbound[w][l] = off[min(bm + w*8 + l, N)];

  {
    int e0   = sbound[w][0];
    int eEnd = sbound[w][8];
    int cur = 0;
    int nb = sbound[w][1];
    float ax = 0.f, ay = 0.f;
    auto flushTo = [&](int edge){
      while(edge >= nb){
        int row = w*8 + cur;
        Albs[(row*256 + ((l*4) ^ ((row&7)<<4))) >> 2] = packbf(ax, ay);
        ax = 0.f; ay = 0.f; ++cur; nb = sbound[w][cur + 1];
      }
    };
    auto loadb = [&](unsigned (&buf)[16], int ebase){
      #pragma unroll
      for(int k = 0; k < 16; ++k){
        int idx = csr_src[ebase + k];
        buf[k] = mu[(size_t)idx*64 + l];
      }
    };
    auto procb = [&](unsigned (&buf)[16], int ebase){
      #pragma unroll
      for(int k = 0; k < 16; ++k){
        flushTo(ebase + k);
        ax += bflo(buf[k]); ay += bfhi(buf[k]);
      }
    };
    int nfull = (eEnd - e0) >> 4;
    unsigned va[16], vb[16];
    int b = 0;
    if(nfull > 0) loadb(va, e0);
    for(; b + 2 <= nfull; b += 2){
      loadb(vb, e0 + (b+1)*16);
      procb(va, e0 + b*16);
      if(b + 2 < nfull) loadb(va, e0 + (b+2)*16);
      procb(vb, e0 + (b+1)*16);
    }
    if(b < nfull) procb(va, e0 + b*16);
    int e = e0 + nfull*16;
    // tail batch (1..15 edges, clamped loads, predicated adds)
    if(e < eEnd){
      #pragma unroll
      for(int k = 0; k < 16; ++k){
        int idx = csr_src[min(e + k, eEnd - 1)];
        va[k] = mu[(size_t)idx*64 + l];
      }
      #pragma unroll
      for(int k = 0; k < 16; ++k){
        if(e + k >= eEnd) break;
        flushTo(e + k);
        ax += bflo(va[k]); ay += bfhi(va[k]);
      }
    }
    // flush remaining nodes (incl. zero-degree / padding rows)
    for(; cur < 8; ++cur){
      int row = w*8 + cur;
      Albs[(row*256 + ((l*4) ^ ((row&7)<<4))) >> 2] = packbf(ax, ay);
      ax = 0.f; ay = 0.f;
    }
  }
  __syncthreads();

  // MFMA: wave (wm,wn) -> rows wm*16..+16, cols wn*64..+64
  int lr = l & 15, lg = l >> 4;
  int wm = w & 3, wn = w >> 2;
  f32x4 acc[4];
  #pragma unroll
  for(int i = 0; i < 4; ++i) acc[i] = (f32x4)0.f;
  int arow = wm*16 + lr;
  #pragma unroll
  for(int ks = 0; ks < 4; ++ks){
    short8 a = *(const short8*)((const char*)shf + arow*256 + ((((ks*4+lg)*16) ^ ((arow&7)<<4))));
    #pragma unroll
    for(int ct = 0; ct < 4; ++ct){
      short8 b = WT[(size_t)(wn*64 + ct*16 + lr)*16 + ks*4 + lg];
      acc[ct] = __builtin_amdgcn_mfma_f32_16x16x32_bf16(a, b, acc[ct], 0, 0, 0);
    }
  }
  __syncthreads();   // all waves done reading A

  // chunked C transpose + epilogue (+baseB, lrelu, pack)
  int r = t >> 3, seg = t & 7;
  int row = bm + r;
  #pragma unroll
  for(int h = 0; h < 2; ++h){
    if(wn == h){
      #pragma unroll
      for(int ct = 0; ct < 4; ++ct)
        #pragma unroll
        for(int rr = 0; rr < 4; ++rr)
          shf[(wm*16 + lg*4 + rr)*68 + ct*16 + lr] = acc[ct][rr];
    }
    __syncthreads();
    if(row < N){
      float4 v0 = *(const float4*)&shf[r*68 + seg*8];
      float4 v1 = *(const float4*)&shf[r*68 + seg*8 + 4];
      const unsigned* ad = baseB + (size_t)row*64 + h*32 + seg*4;
      unsigned b0 = ad[0], b1u = ad[1], b2u = ad[2], b3u = ad[3];
      *(uint4*)&Out[(size_t)row*64 + h*32 + seg*4] = make_uint4(
        packbf(lrelu(v0.x + bflo(b0)),  lrelu(v0.y + bfhi(b0))),
        packbf(lrelu(v0.z + bflo(b1u)), lrelu(v0.w + bfhi(b1u))),
        packbf(lrelu(v1.x + bflo(b2u)), lrelu(v1.y + bfhi(b2u))),
        packbf(lrelu(v1.z + bflo(b3u)), lrelu(v1.w + bfhi(b3u))));
    }
    __syncthreads();
  }
}

// ---------------- two-stage graph mean + sigmoid head ----------------
#define GSB 256
__global__ void k_gsum(const unsigned* __restrict__ mu, const int* __restrict__ batch, int N,
                       float* __restrict__ gsum){
  int c = threadIdx.x & 63, sub = threadIdx.x >> 6;
  int n0 = blockIdx.x * GSB;
  int n1 = min(n0 + GSB, N);
  float ax = 0.f, ay = 0.f; int curg = -1;
  for(int n = n0 + sub; n < n1; n += 4){
    int g = batch[n];
    if(g != curg){
      if(curg >= 0){ atomicAdd(&gsum[curg*P + 2*c], ax); atomicAdd(&gsum[curg*P + 2*c + 1], ay); }
      curg = g; ax = 0.f; ay = 0.f;
    }
    unsigned v = mu[(size_t)n*64 + c];
    ax += bflo(v); ay += bfhi(v);
  }
  if(curg >= 0){ atomicAdd(&gsum[curg*P + 2*c], ax); atomicAdd(&gsum[curg*P + 2*c + 1], ay); }
}

__global__ void k_out(const float* __restrict__ gsum, const int* __restrict__ batch, int N,
                      const float* __restrict__ Wc, const float* __restrict__ bc,
                      float* __restrict__ out){
  int g = blockIdx.x, t = threadIdx.x;
  int lo = 0, hi = N;
  while(lo < hi){ int m=(lo+hi)>>1; if(batch[m] < g) lo = m+1; else hi = m; }
  int start = lo; lo = start; hi = N;
  while(lo < hi){ int m=(lo+hi)>>1; if(batch[m] <= g) lo = m+1; else hi = m; }
  int cnt = lo - start;
  float cf = cnt < 1 ? 1.f : (float)cnt;
  __shared__ float red[128];
  red[t] = (gsum[g*P + t] / cf) * Wc[t];
  __syncthreads();
  for(int o = 64; o > 0; o >>= 1){ if(t < o) red[t] += red[t+o]; __syncthreads(); }
  if(t == 0) out[g] = 1.f/(1.f + expf(-(red[0] + bc[0])));
}

extern "C" void kernel_launch(void* const* d_in, const int* in_sizes, int n_in,
                              void* d_out, int out_size, void* d_ws, size_t ws_size,
                              hipStream_t stream){
  const float* edge_attr = (const float*)d_in[0];
  const float* node_mu   = (const float*)d_in[1];
  const float* xv = (const float*)d_in[2];
  const float* xp = (const float*)d_in[3];
  const float* xd = (const float*)d_in[4];
  const float* W1 = (const float*)d_in[5];  const float* b1 = (const float*)d_in[6];
  const float* W2 = (const float*)d_in[7];  const float* b2 = (const float*)d_in[8];
  const float* W3 = (const float*)d_in[9];  const float* b3 = (const float*)d_in[10];
  const float* Wv = (const float*)d_in[11]; const float* bv = (const float*)d_in[12];
  const float* Wp = (const float*)d_in[13]; const float* bp = (const float*)d_in[14];
  const float* Wd = (const float*)d_in[15]; const float* bd = (const float*)d_in[16];
  const float* Wc = (const float*)d_in[17]; const float* bc = (const float*)d_in[18];
  const int*   ei    = (const int*)d_in[19];
  const int*   batch = (const int*)d_in[21];
  const int E   = in_sizes[0];
  const int N   = in_sizes[1] / P;
  const int NV  = in_sizes[2] / 2;
  const int NP_ = in_sizes[3] / 3;
  const int G   = 64;
  float* out = (float*)d_out;

  char* w = (char*)d_ws; size_t o = 0;
  auto alloc = [&](size_t bytes)->void*{ size_t a = (o + 255) & ~(size_t)255; o = a + bytes; return (void*)(w + a); };
  int*      cntcur   = (int*)     alloc((size_t)2*N*4);    // cnt | cur (one memset)
  int*      off      = (int*)     alloc((size_t)(N+1)*4);
  int*      partial  = (int*)     alloc(512*4);
  int*      csr_src  = (int*)     alloc((size_t)E*4);
  float*    csr_attr = (float*)   alloc((size_t)E*4);
  unsigned* mu0      = (unsigned*)alloc((size_t)N*64*4);   // bf16 pairs
  unsigned* YA       = (unsigned*)alloc((size_t)N*64*4);   // ping
  unsigned* YB       = (unsigned*)alloc((size_t)N*64*4);   // pong
  unsigned* baseB    = (unsigned*)alloc((size_t)N*64*4);   // b1+b2+t_term+type_add (bf16)
  unsigned* W1T      = (unsigned*)alloc((size_t)P*64*4);
  unsigned* W2T      = (unsigned*)alloc((size_t)P*64*4);
  unsigned* W2Tx     = (unsigned*)alloc((size_t)P*16*4);   // extended-K B rows
  float*    gsum     = (float*)   alloc((size_t)G*P*4);
  int* cnt = cntcur; int* cur = cntcur + N;

  hipMemsetAsync(cntcur, 0, (size_t)2*N*4, stream);
  hipMemsetAsync(gsum,   0, (size_t)G*P*4, stream);

  int nb = (N + 255) / 256;
  int ge4 = (E/4 + 255) / 256;
  k_hist   <<<ge4,  256, 0, stream>>>(ei + E, E, cnt);
  k_scan1  <<<nb,   256, 0, stream>>>(cnt, N, off, partial);
  k_scan2  <<<1,    512, 0, stream>>>(partial, nb);
  k_scan3  <<<nb,   256, 0, stream>>>(cnt, N, E, off, partial);
  k_scatter<<<ge4,  256, 0, stream>>>(ei, edge_attr, E, off, cur, csr_src, csr_attr);

  int nhalf = N*64;
  k_cvt  <<<(nhalf + 255)/256, 256, 0, stream>>>((const float2*)node_mu, mu0, nhalf);
  k_wprep<<<257, 128, 0, stream>>>(W1, W2, W1T, W2T, Wv, bv, Wp, bp, Wd, bd, b1, b2, W2Tx);

  int ggemm = (N + 63) / 64;
  k_gemmB<<<ggemm, 512, 0, stream>>>(off, csr_attr, W3, b3,
                                     (const short8*)W2T, (const short8*)W2Tx,
                                     xv, xp, xd, NV, NP_, N, baseB);

  k_fused<<<ggemm, 512, 0, stream>>>(off, csr_src, mu0, (const short8*)W1T, baseB, YA, N);
  k_fused<<<ggemm, 512, 0, stream>>>(off, csr_src, YA,  (const short8*)W1T, baseB, YB, N);
  k_fused<<<ggemm, 512, 0, stream>>>(off, csr_src, YB,  (const short8*)W1T, baseB, YA, N);
  k_fused<<<ggemm, 512, 0, stream>>>(off, csr_src, YA,  (const short8*)W1T, baseB, YB, N);

  k_gsum<<<(N + GSB - 1)/GSB, 256, 0, stream>>>(YB, batch, N, gsum);
  k_out <<<G, P, 0, stream>>>(gsum, batch, N, Wc, bc, out);
}

// Round 10
// 556.188 us; speedup vs baseline: 1.0414x; 1.0414x over previous
//
#include <hip/hip_runtime.h>
#include <math.h>

#define P 128

typedef __attribute__((ext_vector_type(8))) short short8;
typedef __attribute__((ext_vector_type(4))) float f32x4;

static __device__ __forceinline__ float lrelu(float x){ return x > 0.f ? x : 0.01f*x; }
static __device__ __forceinline__ float bflo(unsigned u){ union{unsigned u; float f;} c; c.u = u << 16; return c.f; }
static __device__ __forceinline__ float bfhi(unsigned u){ union{unsigned u; float f;} c; c.u = u & 0xffff0000u; return c.f; }
static __device__ __forceinline__ unsigned fbits(float f){ union{float f; unsigned u;} c; c.f = f; return c.u; }
// round-to-nearest-even f32->bf16, packed pair (lo = first)
static __device__ __forceinline__ unsigned packbf(float x, float y){
  unsigned ux = fbits(x); ux += 0x7fffu + ((ux >> 16) & 1u);
  unsigned uy = fbits(y); uy += 0x7fffu + ((uy >> 16) & 1u);
  return (ux >> 16) | (uy & 0xffff0000u);
}

// ---------------- CSR build (by dst) ----------------
__global__ void k_hist(const int* __restrict__ dst, int E, int* __restrict__ cnt){
  int i = blockIdx.x*blockDim.x + threadIdx.x;
  int i4 = i*4;
  if(i4 + 4 <= E){
    int4 d = *(const int4*)(dst + i4);
    atomicAdd(&cnt[d.x], 1); atomicAdd(&cnt[d.y], 1);
    atomicAdd(&cnt[d.z], 1); atomicAdd(&cnt[d.w], 1);
  } else {
    for(int j = i4; j < E; ++j) atomicAdd(&cnt[dst[j]], 1);
  }
}

__global__ void k_scan1(const int* __restrict__ cnt, int N, int* __restrict__ off, int* __restrict__ partial){
  __shared__ int s[256];
  int t = threadIdx.x, i = blockIdx.x*256 + t;
  int v = (i < N) ? cnt[i] : 0;
  s[t] = v; __syncthreads();
  for(int o = 1; o < 256; o <<= 1){
    int x = (t >= o) ? s[t-o] : 0; __syncthreads();
    s[t] += x; __syncthreads();
  }
  if(i < N) off[i] = s[t];
  if(t == 255) partial[blockIdx.x] = s[255];
}

__global__ void k_scan2(int* __restrict__ partial, int nb){
  __shared__ int s[512];
  int t = threadIdx.x;
  int v = (t < nb) ? partial[t] : 0;
  s[t] = v; __syncthreads();
  for(int o = 1; o < 512; o <<= 1){
    int x = (t >= o) ? s[t-o] : 0; __syncthreads();
    s[t] += x; __syncthreads();
  }
  if(t < nb) partial[t] = s[t] - v;
}

__global__ void k_scan3(const int* __restrict__ cnt, int N, int E, int* __restrict__ off, const int* __restrict__ partial){
  int i = blockIdx.x*256 + threadIdx.x;
  if(i < N) off[i] = off[i] - cnt[i] + partial[blockIdx.x];
  if(i == 0) off[N] = E;
}

// scatter into interleaved CSR: csr[p] = {src, attr_bits} -> ONE 8B store per edge
__global__ void k_scatter(const int* __restrict__ ei, const float* __restrict__ ea, int E,
                          const int* __restrict__ off, int* __restrict__ cur,
                          int2* __restrict__ csr){
  const int* src = ei; const int* dst = ei + E;
  int i = blockIdx.x*blockDim.x + threadIdx.x;
  int i4 = i*4;
  if(i4 + 4 <= E){
    int4   s = *(const int4*)(src + i4);
    int4   d = *(const int4*)(dst + i4);
    float4 a = *(const float4*)(ea + i4);
    int p0 = off[d.x] + atomicAdd(&cur[d.x], 1);
    int p1 = off[d.y] + atomicAdd(&cur[d.y], 1);
    int p2 = off[d.z] + atomicAdd(&cur[d.z], 1);
    int p3 = off[d.w] + atomicAdd(&cur[d.w], 1);
    csr[p0] = make_int2(s.x, __float_as_int(a.x));
    csr[p1] = make_int2(s.y, __float_as_int(a.y));
    csr[p2] = make_int2(s.z, __float_as_int(a.z));
    csr[p3] = make_int2(s.w, __float_as_int(a.w));
  } else {
    for(int j = i4; j < E; ++j){
      int d = dst[j];
      int p = off[d] + atomicAdd(&cur[d], 1);
      csr[p] = make_int2(src[j], __float_as_int(ea[j]));
    }
  }
}

// ---------------- weight prep + mu f32->bf16 conversion (merged) ----------------
// blocks 0..127 -> W1T, 128..255 -> W2T, 256 -> W2Tx, 257.. -> mu cvt
__global__ void k_wprep(const float* __restrict__ W1, const float* __restrict__ W2,
                        unsigned* __restrict__ W1T, unsigned* __restrict__ W2T,
                        const float* __restrict__ Wv, const float* __restrict__ bv,
                        const float* __restrict__ Wp, const float* __restrict__ bp,
                        const float* __restrict__ Wd, const float* __restrict__ bd,
                        const float* __restrict__ b1, const float* __restrict__ b2,
                        unsigned* __restrict__ W2Tx,
                        const float4* __restrict__ mu_in, uint2* __restrict__ mu0v, int npairs){
  int b = blockIdx.x, t = threadIdx.x;
  if(b < 256){
    if(t < 64){
      const float* W = (b < 128) ? W1 : W2;
      unsigned* WT   = (b < 128) ? W1T : W2T;
      int j = b & 127, k2 = t;
      float a = W[(size_t)(2*k2)*P + j], c = W[(size_t)(2*k2+1)*P + j];
      WT[(size_t)j*64 + k2] = packbf(a, c);
    }
  } else if(b == 256){
    // extra B: [j][16 u32] covering k-slots 128..159
    int j = t;  // 128 threads
    unsigned q[16];
    #pragma unroll
    for(int i = 0; i < 16; ++i) q[i] = 0;
    q[0] = packbf(Wv[j],     Wv[128+j]);
    q[1] = packbf(Wp[j],     Wp[128+j]);
    q[2] = packbf(Wp[256+j], Wd[j]);
    q[3] = packbf(Wd[128+j], b1[j] + b2[j]);
    q[4] = packbf(bv[j],     bp[j]);
    q[5] = packbf(bd[j],     0.f);
    uint4* dst = (uint4*)(W2Tx + (size_t)j*16);
    #pragma unroll
    for(int i = 0; i < 4; ++i) dst[i] = make_uint4(q[4*i], q[4*i+1], q[4*i+2], q[4*i+3]);
  } else {
    int i = (b - 257)*128 + t;
    if(i < npairs){
      float4 v = mu_in[i];
      mu0v[i] = make_uint2(packbf(v.x, v.y), packbf(v.z, v.w));
    }
  }
}

// ============ base builder: baseB = [aggt | xfeat] @ [W2 | Wtype]^T  (extended K=160) ============
// block: 512 threads = 8 waves; 64 rows x 128 cols.
__global__ __launch_bounds__(512) void k_gemmB(
    const int* __restrict__ off, const int2* __restrict__ csr,
    const float* __restrict__ W3, const float* __restrict__ b3,
    const short8* __restrict__ WT, const short8* __restrict__ WTx,
    const float* __restrict__ xv, const float* __restrict__ xp, const float* __restrict__ xd,
    int NV, int NP_, int N, unsigned* __restrict__ Out){
  __shared__ __align__(16) unsigned shu[5376];  // A-main u32[0,4096) swizzled; A-extra u32[4096,5376) pitch 20
  __shared__ int sbound[8][9];
  int t = threadIdx.x, w = t >> 6, l = t & 63;
  int bm = blockIdx.x * 64;

  if(l < 9) sbound[w][l] = off[min(bm + w*8 + l, N)];

  // gather phase: flat edge-range walk, batches of 16 contiguous attr loads
  {
    float w0 = W3[2*l], w1 = W3[2*l+1];
    float c0 = b3[2*l], c1 = b3[2*l+1];
    int e0 = sbound[w][0], eEnd = sbound[w][8];
    int cur = 0, nb = sbound[w][1];
    float ax = 0.f, ay = 0.f;
    auto flushTo = [&](int edge){
      while(edge >= nb){
        int row = w*8 + cur;
        shu[(row*256 + ((l*4) ^ ((row&7)<<4))) >> 2] = packbf(ax, ay);
        ax = 0.f; ay = 0.f; ++cur; nb = sbound[w][cur + 1];
      }
    };
    int e = e0;
    for(; e + 16 <= eEnd; e += 16){
      float va[16];
      #pragma unroll
      for(int k = 0; k < 16; ++k) va[k] = __int_as_float(csr[e + k].y);
      #pragma unroll
      for(int k = 0; k < 16; ++k){
        flushTo(e + k);
        ax += lrelu(fmaf(va[k], w0, c0));
        ay += lrelu(fmaf(va[k], w1, c1));
      }
    }
    if(e < eEnd){
      float va[16];
      #pragma unroll
      for(int k = 0; k < 16; ++k) va[k] = __int_as_float(csr[min(e + k, eEnd - 1)].y);
      #pragma unroll
      for(int k = 0; k < 16; ++k){
        if(e + k >= eEnd) break;
        flushTo(e + k);
        ax += lrelu(fmaf(va[k], w0, c0));
        ay += lrelu(fmaf(va[k], w1, c1));
      }
    }
    for(; cur < 8; ++cur){
      int row = w*8 + cur;
      shu[(row*256 + ((l*4) ^ ((row&7)<<4))) >> 2] = packbf(ax, ay);
      ax = 0.f; ay = 0.f;
    }
  }
  // A-extra: row r = t>>3, pair q = t&7 (slots 2q,2q+1); slots 16..31 zero
  {
    int r = t >> 3, q = t & 7;
    int node = bm + r;
    float x0=0.f, x1=0.f, x2=0.f; int ty = 3;
    if(node < N){
      if(node < NV){ ty = 0; x0 = xv[2*node]; x1 = xv[2*node+1]; }
      else if(node < NV + NP_){ int i2 = node - NV; ty = 1; x0 = xp[3*i2]; x1 = xp[3*i2+1]; x2 = xp[3*i2+2]; }
      else { int i2 = node - NV - NP_; ty = 2; x0 = xd[2*i2]; x1 = xd[2*i2+1]; }
    }
    float s0v, s1v;
    switch(q){
      case 0: s0v = (ty==0)?x0:0.f; s1v = (ty==0)?x1:0.f; break;
      case 1: s0v = (ty==1)?x0:0.f; s1v = (ty==1)?x1:0.f; break;
      case 2: s0v = (ty==1)?x2:0.f; s1v = (ty==2)?x0:0.f; break;
      case 3: s0v = (ty==2)?x1:0.f; s1v = (node<N)?1.f:0.f; break;
      case 4: s0v = (ty==0)?1.f:0.f; s1v = (ty==1)?1.f:0.f; break;
      case 5: s0v = (ty==2)?1.f:0.f; s1v = 0.f; break;
      default: s0v = 0.f; s1v = 0.f; break;
    }
    shu[4096 + r*20 + q]     = packbf(s0v, s1v);
    shu[4096 + r*20 + 8 + q] = 0u;
  }
  __syncthreads();

  // MFMA: wave (wm,wn) -> rows wm*16..+16, cols wn*64..+64; K = 160
  int lr = l & 15, lg = l >> 4;
  int wm = w & 3, wn = w >> 2;
  f32x4 acc[4];
  #pragma unroll
  for(int i = 0; i < 4; ++i) acc[i] = (f32x4)0.f;
  int arow = wm*16 + lr;
  #pragma unroll
  for(int ks = 0; ks < 4; ++ks){
    short8 a = *(const short8*)((const char*)shu + arow*256 + ((((ks*4+lg)*16) ^ ((arow&7)<<4))));
    #pragma unroll
    for(int ct = 0; ct < 4; ++ct){
      short8 b = WT[(size_t)(wn*64 + ct*16 + lr)*16 + ks*4 + lg];
      acc[ct] = __builtin_amdgcn_mfma_f32_16x16x32_bf16(a, b, acc[ct], 0, 0, 0);
    }
  }
  {
    short8 a = *(const short8*)&shu[4096 + arow*20 + lg*4];
    #pragma unroll
    for(int ct = 0; ct < 4; ++ct){
      short8 b = WTx[(size_t)(wn*64 + ct*16 + lr)*4 + lg];
      acc[ct] = __builtin_amdgcn_mfma_f32_16x16x32_bf16(a, b, acc[ct], 0, 0, 0);
    }
  }
  __syncthreads();   // A dead; C-chunks may overwrite

  // chunked C transpose + pack (no further epilogue math)
  float* shf = (float*)shu;
  int r = t >> 3, seg = t & 7;
  int row = bm + r;
  #pragma unroll
  for(int h = 0; h < 2; ++h){
    if(wn == h){
      #pragma unroll
      for(int ct = 0; ct < 4; ++ct)
        #pragma unroll
        for(int rr = 0; rr < 4; ++rr)
          shf[(wm*16 + lg*4 + rr)*68 + ct*16 + lr] = acc[ct][rr];
    }
    __syncthreads();
    if(row < N){
      float4 v0 = *(const float4*)&shf[r*68 + seg*8];
      float4 v1 = *(const float4*)&shf[r*68 + seg*8 + 4];
      *(uint4*)&Out[(size_t)row*64 + h*32 + seg*4] =
        make_uint4(packbf(v0.x,v0.y), packbf(v0.z,v0.w), packbf(v1.x,v1.y), packbf(v1.z,v1.w));
    }
    __syncthreads();
  }
}

// ============ fused iteration: Out = lrelu( (segment_sum mu[src]) @ W1^T + baseB ) ============
// block: 512 threads = 8 waves; 64 rows x 128 cols.
// Gather: flat edge-range walk, 16 row-loads per batch (compiler overlaps across batches).
__global__ __launch_bounds__(512) void k_fused(
    const int* __restrict__ off, const int2* __restrict__ csr,
    const unsigned* __restrict__ mu, const short8* __restrict__ WT,
    const unsigned* __restrict__ baseB, unsigned* __restrict__ Out, int N){
  __shared__ __align__(16) float shf[64*68];   // 17408B; front 16KB doubles as swizzled A-tile
  __shared__ int sbound[8][9];
  int t = threadIdx.x, w = t >> 6, l = t & 63;
  int bm = blockIdx.x * 64;
  unsigned* Albs = (unsigned*)shf;

  if(l < 9) sbound[w][l] = off[min(bm + w*8 + l, N)];

  {
    int e0   = sbound[w][0];
    int eEnd = sbound[w][8];
    int cur = 0;
    int nb = sbound[w][1];
    float ax = 0.f, ay = 0.f;
    auto flushTo = [&](int edge){
      while(edge >= nb){
        int row = w*8 + cur;
        Albs[(row*256 + ((l*4) ^ ((row&7)<<4))) >> 2] = packbf(ax, ay);
        ax = 0.f; ay = 0.f; ++cur; nb = sbound[w][cur + 1];
      }
    };
    int e = e0;
    for(; e + 16 <= eEnd; e += 16){
      unsigned v[16];
      #pragma unroll
      for(int k = 0; k < 16; ++k){
        int idx = csr[e + k].x;                      // wave-uniform
        v[k] = mu[(size_t)idx*64 + l];               // 16 independent row loads in flight
      }
      #pragma unroll
      for(int k = 0; k < 16; ++k){
        flushTo(e + k);
        ax += bflo(v[k]); ay += bfhi(v[k]);
      }
    }
    // tail batch (1..15 edges, clamped loads, predicated adds)
    if(e < eEnd){
      unsigned v[16];
      #pragma unroll
      for(int k = 0; k < 16; ++k){
        int idx = csr[min(e + k, eEnd - 1)].x;
        v[k] = mu[(size_t)idx*64 + l];
      }
      #pragma unroll
      for(int k = 0; k < 16; ++k){
        if(e + k >= eEnd) break;
        flushTo(e + k);
        ax += bflo(v[k]); ay += bfhi(v[k]);
      }
    }
    // flush remaining nodes (incl. zero-degree / padding rows)
    for(; cur < 8; ++cur){
      int row = w*8 + cur;
      Albs[(row*256 + ((l*4) ^ ((row&7)<<4))) >> 2] = packbf(ax, ay);
      ax = 0.f; ay = 0.f;
    }
  }
  __syncthreads();

  // MFMA: wave (wm,wn) -> rows wm*16..+16, cols wn*64..+64
  int lr = l & 15, lg = l >> 4;
  int wm = w & 3, wn = w >> 2;
  f32x4 acc[4];
  #pragma unroll
  for(int i = 0; i < 4; ++i) acc[i] = (f32x4)0.f;
  int arow = wm*16 + lr;
  #pragma unroll
  for(int ks = 0; ks < 4; ++ks){
    short8 a = *(const short8*)((const char*)shf + arow*256 + ((((ks*4+lg)*16) ^ ((arow&7)<<4))));
    #pragma unroll
    for(int ct = 0; ct < 4; ++ct){
      short8 b = WT[(size_t)(wn*64 + ct*16 + lr)*16 + ks*4 + lg];
      acc[ct] = __builtin_amdgcn_mfma_f32_16x16x32_bf16(a, b, acc[ct], 0, 0, 0);
    }
  }
  __syncthreads();   // all waves done reading A

  // chunked C transpose + epilogue (+baseB, lrelu, pack)
  int r = t >> 3, seg = t & 7;
  int row = bm + r;
  #pragma unroll
  for(int h = 0; h < 2; ++h){
    if(wn == h){
      #pragma unroll
      for(int ct = 0; ct < 4; ++ct)
        #pragma unroll
        for(int rr = 0; rr < 4; ++rr)
          shf[(wm*16 + lg*4 + rr)*68 + ct*16 + lr] = acc[ct][rr];
    }
    __syncthreads();
    if(row < N){
      float4 v0 = *(const float4*)&shf[r*68 + seg*8];
      float4 v1 = *(const float4*)&shf[r*68 + seg*8 + 4];
      const unsigned* ad = baseB + (size_t)row*64 + h*32 + seg*4;
      unsigned b0 = ad[0], b1u = ad[1], b2u = ad[2], b3u = ad[3];
      *(uint4*)&Out[(size_t)row*64 + h*32 + seg*4] = make_uint4(
        packbf(lrelu(v0.x + bflo(b0)),  lrelu(v0.y + bfhi(b0))),
        packbf(lrelu(v0.z + bflo(b1u)), lrelu(v0.w + bfhi(b1u))),
        packbf(lrelu(v1.x + bflo(b2u)), lrelu(v1.y + bfhi(b2u))),
        packbf(lrelu(v1.z + bflo(b3u)), lrelu(v1.w + bfhi(b3u))));
    }
    __syncthreads();
  }
}

// ---------------- two-stage graph mean + sigmoid head ----------------
#define GSB 256
__global__ void k_gsum(const unsigned* __restrict__ mu, const int* __restrict__ batch, int N,
                       float* __restrict__ gsum){
  int c = threadIdx.x & 63, sub = threadIdx.x >> 6;
  int n0 = blockIdx.x * GSB;
  int n1 = min(n0 + GSB, N);
  float ax = 0.f, ay = 0.f; int curg = -1;
  for(int n = n0 + sub; n < n1; n += 4){
    int g = batch[n];
    if(g != curg){
      if(curg >= 0){ atomicAdd(&gsum[curg*P + 2*c], ax); atomicAdd(&gsum[curg*P + 2*c + 1], ay); }
      curg = g; ax = 0.f; ay = 0.f;
    }
    unsigned v = mu[(size_t)n*64 + c];
    ax += bflo(v); ay += bfhi(v);
  }
  if(curg >= 0){ atomicAdd(&gsum[curg*P + 2*c], ax); atomicAdd(&gsum[curg*P + 2*c + 1], ay); }
}

__global__ void k_out(const float* __restrict__ gsum, const int* __restrict__ batch, int N,
                      const float* __restrict__ Wc, const float* __restrict__ bc,
                      float* __restrict__ out){
  int g = blockIdx.x, t = threadIdx.x;
  int lo = 0, hi = N;
  while(lo < hi){ int m=(lo+hi)>>1; if(batch[m] < g) lo = m+1; else hi = m; }
  int start = lo; lo = start; hi = N;
  while(lo < hi){ int m=(lo+hi)>>1; if(batch[m] <= g) lo = m+1; else hi = m; }
  int cnt = lo - start;
  float cf = cnt < 1 ? 1.f : (float)cnt;
  __shared__ float red[128];
  red[t] = (gsum[g*P + t] / cf) * Wc[t];
  __syncthreads();
  for(int o = 64; o > 0; o >>= 1){ if(t < o) red[t] += red[t+o]; __syncthreads(); }
  if(t == 0) out[g] = 1.f/(1.f + expf(-(red[0] + bc[0])));
}

extern "C" void kernel_launch(void* const* d_in, const int* in_sizes, int n_in,
                              void* d_out, int out_size, void* d_ws, size_t ws_size,
                              hipStream_t stream){
  const float* edge_attr = (const float*)d_in[0];
  const float* node_mu   = (const float*)d_in[1];
  const float* xv = (const float*)d_in[2];
  const float* xp = (const float*)d_in[3];
  const float* xd = (const float*)d_in[4];
  const float* W1 = (const float*)d_in[5];  const float* b1 = (const float*)d_in[6];
  const float* W2 = (const float*)d_in[7];  const float* b2 = (const float*)d_in[8];
  const float* W3 = (const float*)d_in[9];  const float* b3 = (const float*)d_in[10];
  const float* Wv = (const float*)d_in[11]; const float* bv = (const float*)d_in[12];
  const float* Wp = (const float*)d_in[13]; const float* bp = (const float*)d_in[14];
  const float* Wd = (const float*)d_in[15]; const float* bd = (const float*)d_in[16];
  const float* Wc = (const float*)d_in[17]; const float* bc = (const float*)d_in[18];
  const int*   ei    = (const int*)d_in[19];
  const int*   batch = (const int*)d_in[21];
  const int E   = in_sizes[0];
  const int N   = in_sizes[1] / P;
  const int NV  = in_sizes[2] / 2;
  const int NP_ = in_sizes[3] / 3;
  const int G   = 64;
  float* out = (float*)d_out;

  char* w = (char*)d_ws; size_t o = 0;
  auto alloc = [&](size_t bytes)->void*{ size_t a = (o + 255) & ~(size_t)255; o = a + bytes; return (void*)(w + a); };
  int*      cntcur   = (int*)     alloc((size_t)2*N*4);    // cnt | cur (one memset)
  int*      off      = (int*)     alloc((size_t)(N+1)*4);
  int*      partial  = (int*)     alloc(512*4);
  int2*     csr      = (int2*)    alloc((size_t)E*8);      // interleaved {src, attr}
  unsigned* mu0      = (unsigned*)alloc((size_t)N*64*4);   // bf16 pairs
  unsigned* YA       = (unsigned*)alloc((size_t)N*64*4);   // ping
  unsigned* YB       = (unsigned*)alloc((size_t)N*64*4);   // pong
  unsigned* baseB    = (unsigned*)alloc((size_t)N*64*4);   // b1+b2+t_term+type_add (bf16)
  unsigned* W1T      = (unsigned*)alloc((size_t)P*64*4);
  unsigned* W2T      = (unsigned*)alloc((size_t)P*64*4);
  unsigned* W2Tx     = (unsigned*)alloc((size_t)P*16*4);   // extended-K B rows
  float*    gsum     = (float*)   alloc((size_t)G*P*4);
  int* cnt = cntcur; int* cur = cntcur + N;

  hipMemsetAsync(cntcur, 0, (size_t)2*N*4, stream);
  hipMemsetAsync(gsum,   0, (size_t)G*P*4, stream);

  int nb = (N + 255) / 256;
  int ge4 = (E/4 + 255) / 256;
  k_hist   <<<ge4,  256, 0, stream>>>(ei + E, E, cnt);
  k_scan1  <<<nb,   256, 0, stream>>>(cnt, N, off, partial);
  k_scan2  <<<1,    512, 0, stream>>>(partial, nb);
  k_scan3  <<<nb,   256, 0, stream>>>(cnt, N, E, off, partial);
  k_scatter<<<ge4,  256, 0, stream>>>(ei, edge_attr, E, off, cur, csr);

  int npairs = N*32;                       // float4 / uint2 elements for mu conversion
  int gcvt = 257 + (npairs + 127)/128;
  k_wprep<<<gcvt, 128, 0, stream>>>(W1, W2, W1T, W2T, Wv, bv, Wp, bp, Wd, bd, b1, b2, W2Tx,
                                    (const float4*)node_mu, (uint2*)mu0, npairs);

  int ggemm = (N + 63) / 64;
  k_gemmB<<<ggemm, 512, 0, stream>>>(off, csr, W3, b3,
                                     (const short8*)W2T, (const short8*)W2Tx,
                                     xv, xp, xd, NV, NP_, N, baseB);

  k_fused<<<ggemm, 512, 0, stream>>>(off, csr, mu0, (const short8*)W1T, baseB, YA, N);
  k_fused<<<ggemm, 512, 0, stream>>>(off, csr, YA,  (const short8*)W1T, baseB, YB, N);
  k_fused<<<ggemm, 512, 0, stream>>>(off, csr, YB,  (const short8*)W1T, baseB, YA, N);
  k_fused<<<ggemm, 512, 0, stream>>>(off, csr, YA,  (const short8*)W1T, baseB, YB, N);

  k_gsum<<<(N + GSB - 1)/GSB, 256, 0, stream>>>(YB, batch, N, gsum);
  k_out <<<G, P, 0, stream>>>(gsum, batch, N, Wc, bc, out);
}

// Round 11
// 526.639 us; speedup vs baseline: 1.0999x; 1.0561x over previous
//
#include <hip/hip_runtime.h>
#include <math.h>

#define P 128

typedef __attribute__((ext_vector_type(8))) short short8;
typedef __attribute__((ext_vector_type(4))) float f32x4;

static __device__ __forceinline__ float lrelu(float x){ return x > 0.f ? x : 0.01f*x; }
static __device__ __forceinline__ float bflo(unsigned u){ union{unsigned u; float f;} c; c.u = u << 16; return c.f; }
static __device__ __forceinline__ float bfhi(unsigned u){ union{unsigned u; float f;} c; c.u = u & 0xffff0000u; return c.f; }
static __device__ __forceinline__ unsigned fbits(float f){ union{float f; unsigned u;} c; c.f = f; return c.u; }
// round-to-nearest-even f32->bf16, packed pair (lo = first)
static __device__ __forceinline__ unsigned packbf(float x, float y){
  unsigned ux = fbits(x); ux += 0x7fffu + ((ux >> 16) & 1u);
  unsigned uy = fbits(y); uy += 0x7fffu + ((uy >> 16) & 1u);
  return (ux >> 16) | (uy & 0xffff0000u);
}

// ---------------- CSR build (by dst) ----------------
// hist also records each edge's rank within its dst bucket (the atomic's return)
__global__ void k_hist(const int* __restrict__ dst, int E, int* __restrict__ cnt,
                       int* __restrict__ rank){
  int i = blockIdx.x*blockDim.x + threadIdx.x;
  int i4 = i*4;
  if(i4 + 4 <= E){
    int4 d = *(const int4*)(dst + i4);
    int r0 = atomicAdd(&cnt[d.x], 1);
    int r1 = atomicAdd(&cnt[d.y], 1);
    int r2 = atomicAdd(&cnt[d.z], 1);
    int r3 = atomicAdd(&cnt[d.w], 1);
    *(int4*)(rank + i4) = make_int4(r0, r1, r2, r3);
  } else {
    for(int j = i4; j < E; ++j) rank[j] = atomicAdd(&cnt[dst[j]], 1);
  }
}

__global__ void k_scan1(const int* __restrict__ cnt, int N, int* __restrict__ off, int* __restrict__ partial){
  __shared__ int s[256];
  int t = threadIdx.x, i = blockIdx.x*256 + t;
  int v = (i < N) ? cnt[i] : 0;
  s[t] = v; __syncthreads();
  for(int o = 1; o < 256; o <<= 1){
    int x = (t >= o) ? s[t-o] : 0; __syncthreads();
    s[t] += x; __syncthreads();
  }
  if(i < N) off[i] = s[t];
  if(t == 255) partial[blockIdx.x] = s[255];
}

__global__ void k_scan2(int* __restrict__ partial, int nb){
  __shared__ int s[512];
  int t = threadIdx.x;
  int v = (t < nb) ? partial[t] : 0;
  s[t] = v; __syncthreads();
  for(int o = 1; o < 512; o <<= 1){
    int x = (t >= o) ? s[t-o] : 0; __syncthreads();
    s[t] += x; __syncthreads();
  }
  if(t < nb) partial[t] = s[t] - v;
}

__global__ void k_scan3(const int* __restrict__ cnt, int N, int E, int* __restrict__ off, const int* __restrict__ partial){
  int i = blockIdx.x*256 + threadIdx.x;
  if(i < N) off[i] = off[i] - cnt[i] + partial[blockIdx.x];
  if(i == 0) off[N] = E;
}

// atomic-free scatter: position = off[dst] + rank; one 8B store per edge
__global__ void k_scatter(const int* __restrict__ ei, const float* __restrict__ ea, int E,
                          const int* __restrict__ off, const int* __restrict__ rank,
                          int2* __restrict__ csr){
  int i = blockIdx.x*blockDim.x + threadIdx.x;
  if(i < E){
    int d = ei[E + i];
    int p = off[d] + rank[i];
    csr[p] = make_int2(ei[i], __float_as_int(ea[i]));
  }
}

// ---------------- weight prep + mu f32->bf16 conversion (merged) ----------------
// blocks 0..127 -> W1T, 128..255 -> W2T, 256 -> W2Tx, 257.. -> mu cvt
__global__ void k_wprep(const float* __restrict__ W1, const float* __restrict__ W2,
                        unsigned* __restrict__ W1T, unsigned* __restrict__ W2T,
                        const float* __restrict__ Wv, const float* __restrict__ bv,
                        const float* __restrict__ Wp, const float* __restrict__ bp,
                        const float* __restrict__ Wd, const float* __restrict__ bd,
                        const float* __restrict__ b1, const float* __restrict__ b2,
                        unsigned* __restrict__ W2Tx,
                        const float4* __restrict__ mu_in, uint2* __restrict__ mu0v, int npairs){
  int b = blockIdx.x, t = threadIdx.x;
  if(b < 256){
    if(t < 64){
      const float* W = (b < 128) ? W1 : W2;
      unsigned* WT   = (b < 128) ? W1T : W2T;
      int j = b & 127, k2 = t;
      float a = W[(size_t)(2*k2)*P + j], c = W[(size_t)(2*k2+1)*P + j];
      WT[(size_t)j*64 + k2] = packbf(a, c);
    }
  } else if(b == 256){
    // extra B: [j][16 u32] covering k-slots 128..159
    int j = t;  // 128 threads
    unsigned q[16];
    #pragma unroll
    for(int i = 0; i < 16; ++i) q[i] = 0;
    q[0] = packbf(Wv[j],     Wv[128+j]);
    q[1] = packbf(Wp[j],     Wp[128+j]);
    q[2] = packbf(Wp[256+j], Wd[j]);
    q[3] = packbf(Wd[128+j], b1[j] + b2[j]);
    q[4] = packbf(bv[j],     bp[j]);
    q[5] = packbf(bd[j],     0.f);
    uint4* dst = (uint4*)(W2Tx + (size_t)j*16);
    #pragma unroll
    for(int i = 0; i < 4; ++i) dst[i] = make_uint4(q[4*i], q[4*i+1], q[4*i+2], q[4*i+3]);
  } else {
    int i = (b - 257)*128 + t;
    if(i < npairs){
      float4 v = mu_in[i];
      mu0v[i] = make_uint2(packbf(v.x, v.y), packbf(v.z, v.w));
    }
  }
}

// ============ base builder: baseB = [aggt | xfeat] @ [W2 | Wtype]^T  (extended K=160) ============
// block: 512 threads = 8 waves; 64 rows x 128 cols.
__global__ __launch_bounds__(512) void k_gemmB(
    const int* __restrict__ off, const int2* __restrict__ csr,
    const float* __restrict__ W3, const float* __restrict__ b3,
    const short8* __restrict__ WT, const short8* __restrict__ WTx,
    const float* __restrict__ xv, const float* __restrict__ xp, const float* __restrict__ xd,
    int NV, int NP_, int N, unsigned* __restrict__ Out){
  __shared__ __align__(16) unsigned shu[5376];  // A-main u32[0,4096) swizzled; A-extra u32[4096,5376) pitch 20
  __shared__ int sbound[8][9];
  int t = threadIdx.x, w = t >> 6, l = t & 63;
  int bm = blockIdx.x * 64;

  if(l < 9) sbound[w][l] = off[min(bm + w*8 + l, N)];

  // gather phase: flat edge-range walk, batches of 16 contiguous attr loads
  {
    float w0 = W3[2*l], w1 = W3[2*l+1];
    float c0 = b3[2*l], c1 = b3[2*l+1];
    int e0 = sbound[w][0], eEnd = sbound[w][8];
    int cur = 0, nb = sbound[w][1];
    float ax = 0.f, ay = 0.f;
    auto flushTo = [&](int edge){
      while(edge >= nb){
        int row = w*8 + cur;
        shu[(row*256 + ((l*4) ^ ((row&7)<<4))) >> 2] = packbf(ax, ay);
        ax = 0.f; ay = 0.f; ++cur; nb = sbound[w][cur + 1];
      }
    };
    int e = e0;
    for(; e + 16 <= eEnd; e += 16){
      float va[16];
      #pragma unroll
      for(int k = 0; k < 16; ++k) va[k] = __int_as_float(csr[e + k].y);
      #pragma unroll
      for(int k = 0; k < 16; ++k){
        flushTo(e + k);
        ax += lrelu(fmaf(va[k], w0, c0));
        ay += lrelu(fmaf(va[k], w1, c1));
      }
    }
    if(e < eEnd){
      float va[16];
      #pragma unroll
      for(int k = 0; k < 16; ++k) va[k] = __int_as_float(csr[min(e + k, eEnd - 1)].y);
      #pragma unroll
      for(int k = 0; k < 16; ++k){
        if(e + k >= eEnd) break;
        flushTo(e + k);
        ax += lrelu(fmaf(va[k], w0, c0));
        ay += lrelu(fmaf(va[k], w1, c1));
      }
    }
    for(; cur < 8; ++cur){
      int row = w*8 + cur;
      shu[(row*256 + ((l*4) ^ ((row&7)<<4))) >> 2] = packbf(ax, ay);
      ax = 0.f; ay = 0.f;
    }
  }
  // A-extra: row r = t>>3, pair q = t&7 (slots 2q,2q+1); slots 16..31 zero
  {
    int r = t >> 3, q = t & 7;
    int node = bm + r;
    float x0=0.f, x1=0.f, x2=0.f; int ty = 3;
    if(node < N){
      if(node < NV){ ty = 0; x0 = xv[2*node]; x1 = xv[2*node+1]; }
      else if(node < NV + NP_){ int i2 = node - NV; ty = 1; x0 = xp[3*i2]; x1 = xp[3*i2+1]; x2 = xp[3*i2+2]; }
      else { int i2 = node - NV - NP_; ty = 2; x0 = xd[2*i2]; x1 = xd[2*i2+1]; }
    }
    float s0v, s1v;
    switch(q){
      case 0: s0v = (ty==0)?x0:0.f; s1v = (ty==0)?x1:0.f; break;
      case 1: s0v = (ty==1)?x0:0.f; s1v = (ty==1)?x1:0.f; break;
      case 2: s0v = (ty==1)?x2:0.f; s1v = (ty==2)?x0:0.f; break;
      case 3: s0v = (ty==2)?x1:0.f; s1v = (node<N)?1.f:0.f; break;
      case 4: s0v = (ty==0)?1.f:0.f; s1v = (ty==1)?1.f:0.f; break;
      case 5: s0v = (ty==2)?1.f:0.f; s1v = 0.f; break;
      default: s0v = 0.f; s1v = 0.f; break;
    }
    shu[4096 + r*20 + q]     = packbf(s0v, s1v);
    shu[4096 + r*20 + 8 + q] = 0u;
  }
  __syncthreads();

  // MFMA: wave (wm,wn) -> rows wm*16..+16, cols wn*64..+64; K = 160
  int lr = l & 15, lg = l >> 4;
  int wm = w & 3, wn = w >> 2;
  f32x4 acc[4];
  #pragma unroll
  for(int i = 0; i < 4; ++i) acc[i] = (f32x4)0.f;
  int arow = wm*16 + lr;
  #pragma unroll
  for(int ks = 0; ks < 4; ++ks){
    short8 a = *(const short8*)((const char*)shu + arow*256 + ((((ks*4+lg)*16) ^ ((arow&7)<<4))));
    #pragma unroll
    for(int ct = 0; ct < 4; ++ct){
      short8 b = WT[(size_t)(wn*64 + ct*16 + lr)*16 + ks*4 + lg];
      acc[ct] = __builtin_amdgcn_mfma_f32_16x16x32_bf16(a, b, acc[ct], 0, 0, 0);
    }
  }
  {
    short8 a = *(const short8*)&shu[4096 + arow*20 + lg*4];
    #pragma unroll
    for(int ct = 0; ct < 4; ++ct){
      short8 b = WTx[(size_t)(wn*64 + ct*16 + lr)*4 + lg];
      acc[ct] = __builtin_amdgcn_mfma_f32_16x16x32_bf16(a, b, acc[ct], 0, 0, 0);
    }
  }
  __syncthreads();   // A dead; C-chunks may overwrite

  // chunked C transpose + pack (no further epilogue math)
  float* shf = (float*)shu;
  int r = t >> 3, seg = t & 7;
  int row = bm + r;
  #pragma unroll
  for(int h = 0; h < 2; ++h){
    if(wn == h){
      #pragma unroll
      for(int ct = 0; ct < 4; ++ct)
        #pragma unroll
        for(int rr = 0; rr < 4; ++rr)
          shf[(wm*16 + lg*4 + rr)*68 + ct*16 + lr] = acc[ct][rr];
    }
    __syncthreads();
    if(row < N){
      float4 v0 = *(const float4*)&shf[r*68 + seg*8];
      float4 v1 = *(const float4*)&shf[r*68 + seg*8 + 4];
      *(uint4*)&Out[(size_t)row*64 + h*32 + seg*4] =
        make_uint4(packbf(v0.x,v0.y), packbf(v0.z,v0.w), packbf(v1.x,v1.y), packbf(v1.z,v1.w));
    }
    __syncthreads();
  }
}

// ============ fused iteration: Out = lrelu( (segment_sum mu[src]) @ W1^T + baseB ) ============
// block: 512 threads = 8 waves; 64 rows x 128 cols.
// Gather: flat edge-range walk, 16 row-loads per batch (compiler overlaps across batches).
__global__ __launch_bounds__(512) void k_fused(
    const int* __restrict__ off, const int2* __restrict__ csr,
    const unsigned* __restrict__ mu, const short8* __restrict__ WT,
    const unsigned* __restrict__ baseB, unsigned* __restrict__ Out, int N){
  __shared__ __align__(16) float shf[64*68];   // 17408B; front 16KB doubles as swizzled A-tile
  __shared__ int sbound[8][9];
  int t = threadIdx.x, w = t >> 6, l = t & 63;
  int bm = blockIdx.x * 64;
  unsigned* Albs = (unsigned*)shf;

  if(l < 9) sbound[w][l] = off[min(bm + w*8 + l, N)];

  {
    int e0   = sbound[w][0];
    int eEnd = sbound[w][8];
    int cur = 0;
    int nb = sbound[w][1];
    float ax = 0.f, ay = 0.f;
    auto flushTo = [&](int edge){
      while(edge >= nb){
        int row = w*8 + cur;
        Albs[(row*256 + ((l*4) ^ ((row&7)<<4))) >> 2] = packbf(ax, ay);
        ax = 0.f; ay = 0.f; ++cur; nb = sbound[w][cur + 1];
      }
    };
    int e = e0;
    for(; e + 16 <= eEnd; e += 16){
      unsigned v[16];
      #pragma unroll
      for(int k = 0; k < 16; ++k){
        int idx = csr[e + k].x;                      // wave-uniform
        v[k] = mu[(size_t)idx*64 + l];               // 16 independent row loads in flight
      }
      #pragma unroll
      for(int k = 0; k < 16; ++k){
        flushTo(e + k);
        ax += bflo(v[k]); ay += bfhi(v[k]);
      }
    }
    // tail batch (1..15 edges, clamped loads, predicated adds)
    if(e < eEnd){
      unsigned v[16];
      #pragma unroll
      for(int k = 0; k < 16; ++k){
        int idx = csr[min(e + k, eEnd - 1)].x;
        v[k] = mu[(size_t)idx*64 + l];
      }
      #pragma unroll
      for(int k = 0; k < 16; ++k){
        if(e + k >= eEnd) break;
        flushTo(e + k);
        ax += bflo(v[k]); ay += bfhi(v[k]);
      }
    }
    // flush remaining nodes (incl. zero-degree / padding rows)
    for(; cur < 8; ++cur){
      int row = w*8 + cur;
      Albs[(row*256 + ((l*4) ^ ((row&7)<<4))) >> 2] = packbf(ax, ay);
      ax = 0.f; ay = 0.f;
    }
  }
  __syncthreads();

  // MFMA: wave (wm,wn) -> rows wm*16..+16, cols wn*64..+64
  int lr = l & 15, lg = l >> 4;
  int wm = w & 3, wn = w >> 2;
  f32x4 acc[4];
  #pragma unroll
  for(int i = 0; i < 4; ++i) acc[i] = (f32x4)0.f;
  int arow = wm*16 + lr;
  #pragma unroll
  for(int ks = 0; ks < 4; ++ks){
    short8 a = *(const short8*)((const char*)shf + arow*256 + ((((ks*4+lg)*16) ^ ((arow&7)<<4))));
    #pragma unroll
    for(int ct = 0; ct < 4; ++ct){
      short8 b = WT[(size_t)(wn*64 + ct*16 + lr)*16 + ks*4 + lg];
      acc[ct] = __builtin_amdgcn_mfma_f32_16x16x32_bf16(a, b, acc[ct], 0, 0, 0);
    }
  }
  __syncthreads();   // all waves done reading A

  // chunked C transpose + epilogue (+baseB, lrelu, pack)
  int r = t >> 3, seg = t & 7;
  int row = bm + r;
  #pragma unroll
  for(int h = 0; h < 2; ++h){
    if(wn == h){
      #pragma unroll
      for(int ct = 0; ct < 4; ++ct)
        #pragma unroll
        for(int rr = 0; rr < 4; ++rr)
          shf[(wm*16 + lg*4 + rr)*68 + ct*16 + lr] = acc[ct][rr];
    }
    __syncthreads();
    if(row < N){
      float4 v0 = *(const float4*)&shf[r*68 + seg*8];
      float4 v1 = *(const float4*)&shf[r*68 + seg*8 + 4];
      const unsigned* ad = baseB + (size_t)row*64 + h*32 + seg*4;
      unsigned b0 = ad[0], b1u = ad[1], b2u = ad[2], b3u = ad[3];
      *(uint4*)&Out[(size_t)row*64 + h*32 + seg*4] = make_uint4(
        packbf(lrelu(v0.x + bflo(b0)),  lrelu(v0.y + bfhi(b0))),
        packbf(lrelu(v0.z + bflo(b1u)), lrelu(v0.w + bfhi(b1u))),
        packbf(lrelu(v1.x + bflo(b2u)), lrelu(v1.y + bfhi(b2u))),
        packbf(lrelu(v1.z + bflo(b3u)), lrelu(v1.w + bfhi(b3u))));
    }
    __syncthreads();
  }
}

// ---------------- two-stage graph mean + sigmoid head ----------------
#define GSB 256
__global__ void k_gsum(const unsigned* __restrict__ mu, const int* __restrict__ batch, int N,
                       float* __restrict__ gsum){
  int c = threadIdx.x & 63, sub = threadIdx.x >> 6;
  int n0 = blockIdx.x * GSB;
  int n1 = min(n0 + GSB, N);
  float ax = 0.f, ay = 0.f; int curg = -1;
  for(int n = n0 + sub; n < n1; n += 4){
    int g = batch[n];
    if(g != curg){
      if(curg >= 0){ atomicAdd(&gsum[curg*P + 2*c], ax); atomicAdd(&gsum[curg*P + 2*c + 1], ay); }
      curg = g; ax = 0.f; ay = 0.f;
    }
    unsigned v = mu[(size_t)n*64 + c];
    ax += bflo(v); ay += bfhi(v);
  }
  if(curg >= 0){ atomicAdd(&gsum[curg*P + 2*c], ax); atomicAdd(&gsum[curg*P + 2*c + 1], ay); }
}

__global__ void k_out(const float* __restrict__ gsum, const int* __restrict__ batch, int N,
                      const float* __restrict__ Wc, const float* __restrict__ bc,
                      float* __restrict__ out){
  int g = blockIdx.x, t = threadIdx.x;
  int lo = 0, hi = N;
  while(lo < hi){ int m=(lo+hi)>>1; if(batch[m] < g) lo = m+1; else hi = m; }
  int start = lo; lo = start; hi = N;
  while(lo < hi){ int m=(lo+hi)>>1; if(batch[m] <= g) lo = m+1; else hi = m; }
  int cnt = lo - start;
  float cf = cnt < 1 ? 1.f : (float)cnt;
  __shared__ float red[128];
  red[t] = (gsum[g*P + t] / cf) * Wc[t];
  __syncthreads();
  for(int o = 64; o > 0; o >>= 1){ if(t < o) red[t] += red[t+o]; __syncthreads(); }
  if(t == 0) out[g] = 1.f/(1.f + expf(-(red[0] + bc[0])));
}

extern "C" void kernel_launch(void* const* d_in, const int* in_sizes, int n_in,
                              void* d_out, int out_size, void* d_ws, size_t ws_size,
                              hipStream_t stream){
  const float* edge_attr = (const float*)d_in[0];
  const float* node_mu   = (const float*)d_in[1];
  const float* xv = (const float*)d_in[2];
  const float* xp = (const float*)d_in[3];
  const float* xd = (const float*)d_in[4];
  const float* W1 = (const float*)d_in[5];  const float* b1 = (const float*)d_in[6];
  const float* W2 = (const float*)d_in[7];  const float* b2 = (const float*)d_in[8];
  const float* W3 = (const float*)d_in[9];  const float* b3 = (const float*)d_in[10];
  const float* Wv = (const float*)d_in[11]; const float* bv = (const float*)d_in[12];
  const float* Wp = (const float*)d_in[13]; const float* bp = (const float*)d_in[14];
  const float* Wd = (const float*)d_in[15]; const float* bd = (const float*)d_in[16];
  const float* Wc = (const float*)d_in[17]; const float* bc = (const float*)d_in[18];
  const int*   ei    = (const int*)d_in[19];
  const int*   batch = (const int*)d_in[21];
  const int E   = in_sizes[0];
  const int N   = in_sizes[1] / P;
  const int NV  = in_sizes[2] / 2;
  const int NP_ = in_sizes[3] / 3;
  const int G   = 64;
  float* out = (float*)d_out;

  char* w = (char*)d_ws; size_t o = 0;
  auto alloc = [&](size_t bytes)->void*{ size_t a = (o + 255) & ~(size_t)255; o = a + bytes; return (void*)(w + a); };
  int*      cnt      = (int*)     alloc((size_t)N*4);
  int*      rank     = (int*)     alloc((size_t)E*4);      // per-edge rank within dst bucket
  int*      off      = (int*)     alloc((size_t)(N+1)*4);
  int*      partial  = (int*)     alloc(512*4);
  int2*     csr      = (int2*)    alloc((size_t)E*8);      // interleaved {src, attr}
  unsigned* mu0      = (unsigned*)alloc((size_t)N*64*4);   // bf16 pairs
  unsigned* YA       = (unsigned*)alloc((size_t)N*64*4);   // ping
  unsigned* YB       = (unsigned*)alloc((size_t)N*64*4);   // pong
  unsigned* baseB    = (unsigned*)alloc((size_t)N*64*4);   // b1+b2+t_term+type_add (bf16)
  unsigned* W1T      = (unsigned*)alloc((size_t)P*64*4);
  unsigned* W2T      = (unsigned*)alloc((size_t)P*64*4);
  unsigned* W2Tx     = (unsigned*)alloc((size_t)P*16*4);   // extended-K B rows
  float*    gsum     = (float*)   alloc((size_t)G*P*4);

  hipMemsetAsync(cnt,  0, (size_t)N*4, stream);
  hipMemsetAsync(gsum, 0, (size_t)G*P*4, stream);

  int nb = (N + 255) / 256;
  int ge4 = (E/4 + 255) / 256;
  int ge1 = (E + 255) / 256;
  k_hist   <<<ge4,  256, 0, stream>>>(ei + E, E, cnt, rank);
  k_scan1  <<<nb,   256, 0, stream>>>(cnt, N, off, partial);
  k_scan2  <<<1,    512, 0, stream>>>(partial, nb);
  k_scan3  <<<nb,   256, 0, stream>>>(cnt, N, E, off, partial);
  k_scatter<<<ge1,  256, 0, stream>>>(ei, edge_attr, E, off, rank, csr);

  int npairs = N*32;                       // float4 / uint2 elements for mu conversion
  int gcvt = 257 + (npairs + 127)/128;
  k_wprep<<<gcvt, 128, 0, stream>>>(W1, W2, W1T, W2T, Wv, bv, Wp, bp, Wd, bd, b1, b2, W2Tx,
                                    (const float4*)node_mu, (uint2*)mu0, npairs);

  int ggemm = (N + 63) / 64;
  k_gemmB<<<ggemm, 512, 0, stream>>>(off, csr, W3, b3,
                                     (const short8*)W2T, (const short8*)W2Tx,
                                     xv, xp, xd, NV, NP_, N, baseB);

  k_fused<<<ggemm, 512, 0, stream>>>(off, csr, mu0, (const short8*)W1T, baseB, YA, N);
  k_fused<<<ggemm, 512, 0, stream>>>(off, csr, YA,  (const short8*)W1T, baseB, YB, N);
  k_fused<<<ggemm, 512, 0, stream>>>(off, csr, YB,  (const short8*)W1T, baseB, YA, N);
  k_fused<<<ggemm, 512, 0, stream>>>(off, csr, YA,  (const short8*)W1T, baseB, YB, N);

  k_gsum<<<(N + GSB - 1)/GSB, 256, 0, stream>>>(YB, batch, N, gsum);
  k_out <<<G, P, 0, stream>>>(gsum, batch, N, Wc, bc, out);
}